// Round 9
// baseline (516.358 us; speedup 1.0000x reference)
//
#include <hip/hip_runtime.h>

#define NN 50000
#define EE 640000
#define DINv 64
#define GBv 128
#define GDv 4
#define LBv 256
#define LDv 2
#define GGv 1024

#define NB 196       // coarse buckets (256 nodes each)
#define BCAP 4096    // bucket capacity
#define BTILE 4096   // edges per k_bucket block
#define NBT ((EE + BTILE - 1) / BTILE)  // 157

#define NTILES ((NN + 63) / 64)  // 782 row-tiles

typedef _Float16 f16x8 __attribute__((ext_vector_type(8)));
typedef float f32x4 __attribute__((ext_vector_type(4)));

__device__ __forceinline__ float h2f(ushort u) {
  union { ushort u; _Float16 h; } x;
  x.u = u;
  return (float)x.h;
}
__device__ __forceinline__ ushort f2h(float f) {
  union { ushort u; _Float16 h; } x;
  x.h = (_Float16)f;
  return x.u;
}

// ---------------- stage 1: coarse bucket sort (dst>>8) ----------------

__global__ __launch_bounds__(256) void k_bucket(const int* __restrict__ ei,
                                                int* __restrict__ bcnt,
                                                uint* __restrict__ bkt) {
  __shared__ int lcnt[NB];
  __shared__ int lbase[NB];
  __shared__ int gbase[NB];
  __shared__ int ls[256];
  __shared__ uint stage[BTILE];
  __shared__ ushort sb[BTILE];
  int tid = threadIdx.x;
  int t0 = blockIdx.x * BTILE;
  int cnt = min(BTILE, EE - t0);
  for (int i = tid; i < NB; i += 256) lcnt[i] = 0;
  __syncthreads();

  uint en[16];
  int bb[16], rk[16];
  int nper = (cnt + 255) >> 8;
  for (int k = 0; k < nper; k++) {
    int e = k * 256 + tid;
    if (e < cnt) {
      int src = ei[t0 + e];
      int dst = ei[EE + t0 + e];
      int b = dst >> 8;
      en[k] = ((uint)src << 8) | (uint)(dst & 255);
      bb[k] = b;
      rk[k] = atomicAdd(&lcnt[b], 1);
    } else {
      bb[k] = -1;
    }
  }
  __syncthreads();

  int v = (tid < NB) ? lcnt[tid] : 0;
  ls[tid] = v;
  __syncthreads();
  for (int off = 1; off < 256; off <<= 1) {
    int t = (tid >= off) ? ls[tid - off] : 0;
    __syncthreads();
    ls[tid] += t;
    __syncthreads();
  }
  if (tid < NB) {
    lbase[tid] = ls[tid] - v;
    gbase[tid] = atomicAdd(&bcnt[tid], v);
  }
  __syncthreads();

  for (int k = 0; k < nper; k++) {
    if (bb[k] >= 0) {
      int slot = lbase[bb[k]] + rk[k];
      stage[slot] = en[k];
      sb[slot] = (ushort)bb[k];
    }
  }
  __syncthreads();

  for (int i = tid; i < cnt; i += 256) {
    int b = sb[i];
    bkt[(size_t)b * BCAP + gbase[b] + (i - lbase[b])] = stage[i];
  }
}

__global__ __launch_bounds__(256) void k_bscan(const int* __restrict__ bcnt,
                                               int* __restrict__ bbase,
                                               int* __restrict__ offs) {
  __shared__ int ls[256];
  int tid = threadIdx.x;
  int v = (tid < NB) ? bcnt[tid] : 0;
  ls[tid] = v;
  __syncthreads();
  for (int off = 1; off < 256; off <<= 1) {
    int t = (tid >= off) ? ls[tid - off] : 0;
    __syncthreads();
    ls[tid] += t;
    __syncthreads();
  }
  if (tid < NB) bbase[tid] = ls[tid] - v;
  if (tid == 0) offs[NN] = EE;
}

// ---------------- stage 2: per-bucket fine CSR + deg/dinv/offs ----------------

__global__ __launch_bounds__(256) void k_csr(const uint* __restrict__ bkt,
                                             const int* __restrict__ bcnt,
                                             const int* __restrict__ bbase,
                                             int* __restrict__ offs,
                                             float* __restrict__ dinv,
                                             int* __restrict__ col) {
  __shared__ int lhist[256];
  __shared__ int lofs[256];
  __shared__ int lcur[256];
  int b = blockIdx.x;
  int cnt = bcnt[b], base = bbase[b];
  const uint* B = bkt + (size_t)b * BCAP;
  int tid = threadIdx.x;
  lhist[tid] = 0;
  __syncthreads();
  for (int i = tid; i < cnt; i += 256) atomicAdd(&lhist[B[i] & 255], 1);
  __syncthreads();
  int v = lhist[tid];
  lofs[tid] = v;
  __syncthreads();
  for (int off = 1; off < 256; off <<= 1) {
    int t = (tid >= off) ? lofs[tid - off] : 0;
    __syncthreads();
    lofs[tid] += t;
    __syncthreads();
  }
  int excl = lofs[tid] - v;
  int n = b * 256 + tid;
  if (n < NN) {
    offs[n] = base + excl;
    dinv[n] = rsqrtf((float)(v + 1));
  }
  lcur[tid] = excl;
  __syncthreads();
  for (int i = tid; i < cnt; i += 256) {
    uint e = B[i];
    int p = atomicAdd(&lcur[e & 255], 1);
    col[base + p] = (int)(e >> 8);
  }
}

// ---------------- weight transpose+convert: Wt[c][k] = f16(W[k][c]) ----------------

__global__ void k_convW(const float* __restrict__ W0, const float* __restrict__ Wg,
                        ushort* __restrict__ Wt0, ushort* __restrict__ Wtg) {
  int idx = blockIdx.x * 256 + threadIdx.x;
  if (idx < DINv * GBv) {
    int c = idx >> 6, k = idx & 63;
    Wt0[idx] = f2h(W0[k * GBv + c]);
  } else if (idx < DINv * GBv + GDv * GBv * GBv) {
    int e = idx - DINv * GBv;
    int i = e >> 14, rem = e & 16383;
    int c = rem >> 7, k = rem & 127;
    Wtg[e] = f2h(Wg[i * GBv * GBv + k * GBv + c]);
  }
}

// ---------------- u = x * dinv  (f16, 64-dim) ----------------

__global__ __launch_bounds__(256) void k_uprep(const float* __restrict__ x,
                                               const float* __restrict__ dinv,
                                               ushort* __restrict__ u) {
  int i = blockIdx.x * 256 + threadIdx.x;
  if (i >= NN * 16) return;
  int n = i >> 4;
  float4 v = ((const float4*)x)[i];
  float d = dinv[n];
  union { ushort us[4]; uint2 q; } o;
  o.us[0] = f2h(v.x * d);
  o.us[1] = f2h(v.y * d);
  o.us[2] = f2h(v.z * d);
  o.us[3] = f2h(v.w * d);
  ((uint2*)u)[i] = o.q;
}

// ---------------- CSR aggregate, COLUMN-SPLIT for L2 residency ----------------
// Pass p (of K/32) gathers only cols [32p, 32p+32): working set 3.2 MB -> fits
// one XCD L2. Grid is pass-major so co-resident blocks share a pass; a 52 KB
// LDS pad caps residency at 3 blocks/CU (~768 blocks ~ one pass of 782).
// 16 nodes/wave, 4 lanes/node, uint4 (8 halves = 32 cols) per lane.
// V[n][c] = f16( dinv[n] * ( row(n)[c] + sum_src row(src)[c] ) )
// row(s) = MODE0: Gin[s]; MODE1: relu(Gin[s])*dinv[s]; MODE2: relu(Gin[s]*S+T)*dinv[s]

template <int K, int MODE>
__global__ __launch_bounds__(256) void k_agg(const ushort* __restrict__ Gin,
                                             const int* __restrict__ col,
                                             const int* __restrict__ offs,
                                             const float* __restrict__ dinv,
                                             const float* __restrict__ st,
                                             const float* __restrict__ gamma,
                                             const float* __restrict__ beta,
                                             ushort* __restrict__ V) {
  __shared__ int pad[13312];  // 52 KB: caps occupancy at 3 blocks/CU (residency)
  int tid = threadIdx.x;
  if (offs[NN] == -1) {  // never true (offs[NN]==EE); keeps pad allocated
    pad[tid] = tid;
    __syncthreads();
    V[pad[tid]] = 0;
  }

  int pass = blockIdx.x / NTILES;
  int tile = blockIdx.x - pass * NTILES;
  int row0 = tile * 64;
  int w = tid >> 6, lane = tid & 63;
  int gnode = lane >> 2;   // node within wave: 0..15
  int l4 = lane & 3;       // lane within node
  int n = row0 + w * 16 + gnode;
  int cbase = pass * 32 + l4 * 8;  // first of this lane's 8 columns
  if (n >= NN) return;

  float sc[8], tc[8];
  if constexpr (MODE == 2) {
#pragma unroll
    for (int v = 0; v < 8; v++) {
      int c = cbase + v;
      float mu = st[c] * (1.f / NN);
      float var = st[128 + c] * (1.f / NN) - mu * mu;
      float s = rsqrtf(var + 1e-5f) * gamma[c];
      sc[v] = s;
      tc[v] = beta[c] - mu * s;
    }
  }

  union U { uint4 v4; ushort us[8]; };
  auto loadrow = [&](int s) {
    U u;
    u.v4 = *(const uint4*)(Gin + (long)s * K + cbase);
    return u;
  };
  float acc[8];
#pragma unroll
  for (int v = 0; v < 8; v++) acc[v] = 0.f;
  auto addrow = [&](U u, float dv) {
#pragma unroll
    for (int v = 0; v < 8; v++) {
      float g = h2f(u.us[v]);
      if constexpr (MODE == 0) acc[v] += g;
      else if constexpr (MODE == 1) acc[v] += fmaxf(g, 0.f) * dv;
      else acc[v] += fmaxf(g * sc[v] + tc[v], 0.f) * dv;
    }
  };

  float dn = dinv[n];
  addrow(loadrow(n), dn);  // self term

  int s0 = offs[n], s1 = offs[n + 1];
  int j = s0;
  for (; j + 7 < s1; j += 8) {
    int si[8];
#pragma unroll
    for (int t = 0; t < 8; t++) si[t] = col[j + t];
    U uu[8];
#pragma unroll
    for (int t = 0; t < 8; t++) uu[t] = loadrow(si[t]);
    float dd[8];
#pragma unroll
    for (int t = 0; t < 8; t++) dd[t] = (MODE != 0) ? dinv[si[t]] : 0.f;
#pragma unroll
    for (int t = 0; t < 8; t++) addrow(uu[t], dd[t]);
  }
  for (; j + 3 < s1; j += 4) {
    int si[4];
#pragma unroll
    for (int t = 0; t < 4; t++) si[t] = col[j + t];
    U uu[4];
#pragma unroll
    for (int t = 0; t < 4; t++) uu[t] = loadrow(si[t]);
    float dd[4];
#pragma unroll
    for (int t = 0; t < 4; t++) dd[t] = (MODE != 0) ? dinv[si[t]] : 0.f;
#pragma unroll
    for (int t = 0; t < 4; t++) addrow(uu[t], dd[t]);
  }
  for (; j < s1; j++) {
    int s = col[j];
    U u = loadrow(s);
    float dv = (MODE != 0) ? dinv[s] : 0.f;
    addrow(u, dv);
  }

  U o;
#pragma unroll
  for (int v = 0; v < 8; v++) o.us[v] = f2h(acc[v] * dn);
  *(uint4*)(V + (long)n * K + cbase) = o.v4;
}

// ---------------- MFMA matmul: g[r][c] = f16( (V @ W)[r][c] + b[c] ), fused stats ----
// Persistent-W grid-stride, padded LDS strides (conflict-free), register stats.

template <int K, bool STATS>
__global__ __launch_bounds__(256) void k_mm(const ushort* __restrict__ X,
                                            const ushort* __restrict__ Wt,
                                            const float* __restrict__ bias,
                                            float* __restrict__ stG,
                                            ushort* __restrict__ Gout) {
  constexpr int KP = K + 8;
  constexpr int CP = 136;
  constexpr bool REUSE = (K == 128);
  __shared__ __attribute__((aligned(16))) _Float16 sW[128 * KP];
  __shared__ __attribute__((aligned(16))) _Float16 sA[64 * KP];
  __shared__ __attribute__((aligned(16))) _Float16 sCbuf[REUSE ? 8 : 64 * CP];
  __shared__ float sB[128];
  __shared__ float ssum[128], ssq[128];
  _Float16* sC = REUSE ? sA : sCbuf;
  int tid = threadIdx.x;

  {
    constexpr int CH = K / 8;
    for (int i = tid; i < 128 * CH; i += 256) {
      int c = i / CH, ch = i - c * CH;
      *(uint4*)&sW[c * KP + ch * 8] = ((const uint4*)Wt)[i];
    }
  }
  if (tid < 128) {
    sB[tid] = bias[tid];
    if constexpr (STATS) {
      ssum[tid] = 0.f;
      ssq[tid] = 0.f;
    }
  }

  int w = tid >> 6, lane = tid & 63;
  int m = lane & 15, quad = lane >> 4;
  int crow = 16 * w + quad * 4;

  float ps[8], pq[8];
  if constexpr (STATS) {
#pragma unroll
    for (int ct = 0; ct < 8; ct++) { ps[ct] = 0.f; pq[ct] = 0.f; }
  }

  for (int tile = blockIdx.x; tile < NTILES; tile += gridDim.x) {
    int row0 = tile * 64;
    __syncthreads();

    {
      int r = tid >> 2, col0 = (tid & 3) * (K / 4);
      int gr = row0 + r;
      const uint4* p = (const uint4*)(X + (long)gr * K + col0);
#pragma unroll
      for (int ch = 0; ch < K / 32; ch++) {
        uint4 v = (gr < NN) ? p[ch] : make_uint4(0, 0, 0, 0);
        *(uint4*)&sA[r * KP + col0 + ch * 8] = v;
      }
    }
    __syncthreads();

    f32x4 acc[8];
#pragma unroll
    for (int ct = 0; ct < 8; ct++) acc[ct] = (f32x4){0.f, 0.f, 0.f, 0.f};
    const _Float16* pa = &sA[(16 * w + m) * KP + quad * 8];
#pragma unroll
    for (int ks = 0; ks < K; ks += 32) {
      f16x8 a = *(const f16x8*)(pa + ks);
#pragma unroll
      for (int ct = 0; ct < 8; ct++) {
        f16x8 b = *(const f16x8*)&sW[(ct * 16 + m) * KP + ks + quad * 8];
        acc[ct] = __builtin_amdgcn_mfma_f32_16x16x32_f16(a, b, acc[ct], 0, 0, 0);
      }
    }

    if constexpr (STATS) {
#pragma unroll
      for (int ct = 0; ct < 8; ct++) {
        int c = ct * 16 + m;
        float b = sB[c];
#pragma unroll
        for (int r = 0; r < 4; r++) {
          if (row0 + crow + r < NN) {
            float g = acc[ct][r] + b;
            ps[ct] += g;
            pq[ct] += g * g;
          }
        }
      }
    }
    if constexpr (REUSE) __syncthreads();

#pragma unroll
    for (int ct = 0; ct < 8; ct++) {
      int c = ct * 16 + m;
      float b = sB[c];
#pragma unroll
      for (int r = 0; r < 4; r++) sC[(crow + r) * CP + c] = (_Float16)(acc[ct][r] + b);
    }
    __syncthreads();

    {
      int r = tid >> 2, col0 = (tid & 3) * 32;
      int gr = row0 + r;
      if (gr < NN) {
        const uint4* src = (const uint4*)&sC[r * CP + col0];
        uint4* dst = (uint4*)(Gout + (long)gr * 128 + col0);
#pragma unroll
        for (int ch = 0; ch < 4; ch++) dst[ch] = src[ch];
      }
    }
  }

  if constexpr (STATS) {
#pragma unroll
    for (int ct = 0; ct < 8; ct++) {
      float s = ps[ct], q = pq[ct];
      s += __shfl_xor(s, 16);
      q += __shfl_xor(q, 16);
      s += __shfl_xor(s, 32);
      q += __shfl_xor(q, 32);
      if (quad == 0) {
        atomicAdd(&ssum[ct * 16 + m], s);
        atomicAdd(&ssq[ct * 16 + m], q);
      }
    }
    __syncthreads();
    if (tid < 128) {
      int c = (tid + blockIdx.x * 8) & 127;
      atomicAdd(&stG[c], ssum[c]);
      atomicAdd(&stG[128 + c], ssq[c]);
    }
  }
}

// ---------------- pool: per-graph segmented reduction (batch sorted) ----------------

__global__ __launch_bounds__(128) void k_pool2(const ushort* __restrict__ G,
                                               const float* __restrict__ st,
                                               const float* __restrict__ gamma,
                                               const float* __restrict__ beta,
                                               const int* __restrict__ batch,
                                               float* __restrict__ hp) {
  __shared__ int sse[2];
  int g = blockIdx.x;
  int c = threadIdx.x;
  if (c < 2) {
    int key = g + c;
    int lo = 0, hi = NN;
    while (lo < hi) {
      int mid = (lo + hi) >> 1;
      if (batch[mid] < key) lo = mid + 1;
      else hi = mid;
    }
    sse[c] = lo;
  }
  __syncthreads();
  int s = sse[0], e = sse[1];
  float m = st[c] * (1.f / NN);
  float v = st[128 + c] * (1.f / NN) - m * m;
  float sc = rsqrtf(v + 1e-5f) * gamma[c];
  float tc = beta[c] - m * sc;
  float acc = 0.f;
  for (int n = s; n < e; n++) acc += fmaxf(h2f(G[(long)n * 128 + c]) * sc + tc, 0.f);
  hp[(long)g * 128 + c] = acc;
}

// ---------------- head column stats (fp32) ----------------

__global__ void k_colstats(const float* __restrict__ X, int rows, float* __restrict__ st) {
  int c = threadIdx.x;
  int C = blockDim.x;
  float s = 0.f, q = 0.f;
  for (int r = blockIdx.x; r < rows; r += gridDim.x) {
    float v = X[(long)r * C + c];
    s += v;
    q += v * v;
  }
  atomicAdd(&st[c], s);
  atomicAdd(&st[C + c], q);
}

// ---------------- MLP head ----------------

template <int KIN, int MODE>
__global__ __launch_bounds__(256) void k_fc(const float* __restrict__ X,
                                            const float* __restrict__ W,
                                            const float* __restrict__ b,
                                            const float* __restrict__ st,
                                            const float* __restrict__ gamma,
                                            const float* __restrict__ beta,
                                            float* __restrict__ Y) {
  __shared__ float sx[KIN];
  int g = blockIdx.x;
  int c = threadIdx.x;
  for (int k = c; k < KIN; k += 256) {
    float v = X[(long)g * KIN + k];
    if constexpr (MODE == 2) {
      float m = st[k] * (1.f / GGv);
      float var = st[KIN + k] * (1.f / GGv) - m * m;
      v = fmaxf((v - m) * rsqrtf(var + 1e-5f) * gamma[k] + beta[k], 0.f);
    }
    sx[k] = v;
  }
  __syncthreads();
  float acc = b[c];
#pragma unroll 8
  for (int k = 0; k < KIN; k++) acc += sx[k] * W[(long)k * 256 + c];
  Y[(long)g * 256 + c] = (MODE == 0) ? fmaxf(acc, 0.f) : acc;
}

__global__ __launch_bounds__(256) void k_out(const float* __restrict__ X,
                                             const float* __restrict__ st,
                                             const float* __restrict__ gamma,
                                             const float* __restrict__ beta,
                                             const float* __restrict__ Wout,
                                             const float* __restrict__ bout,
                                             float* __restrict__ out) {
  int g = blockIdx.x * 4 + (threadIdx.x >> 6);
  int l = threadIdx.x & 63;
  float a0 = 0.f, a1 = 0.f;
  for (int k = l; k < LBv; k += 64) {
    float z = X[(long)g * LBv + k];
    float m = st[k] * (1.f / GGv);
    float var = st[LBv + k] * (1.f / GGv) - m * m;
    float x = fmaxf((z - m) * rsqrtf(var + 1e-5f) * gamma[k] + beta[k], 0.f);
    a0 += x * Wout[2 * k];
    a1 += x * Wout[2 * k + 1];
  }
  for (int off = 32; off > 0; off >>= 1) {
    a0 += __shfl_down(a0, off);
    a1 += __shfl_down(a1, off);
  }
  if (l == 0) {
    out[2 * g] = a0 + bout[0];
    out[2 * g + 1] = a1 + bout[1];
  }
}

// ---------------- launch ----------------

extern "C" void kernel_launch(void* const* d_in, const int* in_sizes, int n_in,
                              void* d_out, int out_size, void* d_ws, size_t ws_size,
                              hipStream_t stream) {
  const float* x = (const float*)d_in[0];
  const int* ei = (const int*)d_in[1];
  const int* batch = (const int*)d_in[2];
  const float* W0 = (const float*)d_in[4];
  const float* b0 = (const float*)d_in[5];
  const float* Wg = (const float*)d_in[6];
  const float* bg = (const float*)d_in[7];
  const float* gamma_g = (const float*)d_in[8];
  const float* beta_g = (const float*)d_in[9];
  const float* Wl0 = (const float*)d_in[10];
  const float* bl0 = (const float*)d_in[11];
  const float* Wl = (const float*)d_in[12];
  const float* bl = (const float*)d_in[13];
  const float* gamma_l = (const float*)d_in[14];
  const float* beta_l = (const float*)d_in[15];
  const float* Wout = (const float*)d_in[16];
  const float* bout = (const float*)d_in[17];
  float* out = (float*)d_out;

  char* w = (char*)d_ws;
  auto alloc = [&](size_t bytes) {
    void* p = (void*)w;
    w += (bytes + 255) & ~(size_t)255;
    return p;
  };
  int* bcnt = (int*)alloc((size_t)NB * 4);
  float* stAll = (float*)alloc((size_t)(4 * 256 + 2 * 512) * 4);
  size_t zspan = (char*)w - (char*)bcnt;
  uint* bkt = (uint*)alloc((size_t)NB * BCAP * 4);
  int* bbase = (int*)alloc((size_t)NB * 4);
  int* offs = (int*)alloc((size_t)(NN + 1) * 4);
  int* col = (int*)alloc((size_t)EE * 4);
  float* dinv = (float*)alloc((size_t)NN * 4);
  ushort* u = (ushort*)alloc((size_t)NN * DINv * 2);
  ushort* V = (ushort*)alloc((size_t)NN * GBv * 2);
  ushort* g = (ushort*)alloc((size_t)NN * GBv * 2);
  ushort* Wt0 = (ushort*)alloc((size_t)DINv * GBv * 2);
  ushort* Wtg = (ushort*)alloc((size_t)GDv * GBv * GBv * 2);
  float* hp = (float*)alloc((size_t)GGv * GBv * 4);
  float* m1 = (float*)alloc((size_t)GGv * LBv * 4);
  float* m2 = (float*)alloc((size_t)GGv * LBv * 4);

  float* stg = stAll;
  float* sth0 = stAll + 4 * 256;
  float* sth1 = sth0 + 512;

  hipMemsetAsync(bcnt, 0, zspan, stream);

  k_bucket<<<NBT, 256, 0, stream>>>(ei, bcnt, bkt);
  k_bscan<<<1, 256, 0, stream>>>(bcnt, bbase, offs);
  k_csr<<<NB, 256, 0, stream>>>(bkt, bcnt, bbase, offs, dinv, col);
  k_convW<<<(DINv * GBv + GDv * GBv * GBv + 255) / 256, 256, 0, stream>>>(W0, Wg, Wt0, Wtg);
  k_uprep<<<(NN * 16 + 255) / 256, 256, 0, stream>>>(x, dinv, u);

  const int MMG = 512;  // persistent-W grid-stride blocks

  // layer 0 (2 column passes for K=64)
  k_agg<64, 0><<<2 * NTILES, 256, 0, stream>>>(u, col, offs, dinv, nullptr, nullptr,
                                               nullptr, V);
  k_mm<64, false><<<MMG, 256, 0, stream>>>(V, Wt0, b0, nullptr, g);

  // layer 1 (relu fold; 4 column passes)
  k_agg<128, 1><<<4 * NTILES, 256, 0, stream>>>(g, col, offs, dinv, nullptr, nullptr,
                                                nullptr, V);
  k_mm<128, true><<<MMG, 256, 0, stream>>>(V, Wtg, bg, stg, g);

  // layers 2..4 (BN+relu fold)
  for (int i = 1; i < GDv; i++) {
    k_agg<128, 2><<<4 * NTILES, 256, 0, stream>>>(g, col, offs, dinv,
                                                  stg + (size_t)(i - 1) * 256,
                                                  gamma_g + (size_t)(i - 1) * GBv,
                                                  beta_g + (size_t)(i - 1) * GBv, V);
    k_mm<128, true><<<MMG, 256, 0, stream>>>(V, Wtg + (size_t)i * GBv * GBv,
                                             bg + (size_t)i * GBv, stg + (size_t)i * 256, g);
  }

  // pool with final BN+relu fused
  k_pool2<<<GGv, 128, 0, stream>>>(g, stg + 3 * 256, gamma_g + 3 * GBv, beta_g + 3 * GBv,
                                   batch, hp);

  // head
  k_fc<GBv, 0><<<GGv, 256, 0, stream>>>(hp, Wl0, bl0, nullptr, nullptr, nullptr, m1);
  k_fc<LBv, 1><<<GGv, 256, 0, stream>>>(m1, Wl, bl, nullptr, nullptr, nullptr, m2);
  k_colstats<<<256, LBv, 0, stream>>>(m2, GGv, sth0);
  k_fc<LBv, 2><<<GGv, 256, 0, stream>>>(m2, Wl + (size_t)LBv * LBv, bl + LBv, sth0,
                                        gamma_l, beta_l, m1);
  k_colstats<<<256, LBv, 0, stream>>>(m1, GGv, sth1);
  k_out<<<GGv / 4, 256, 0, stream>>>(m1, sth1, gamma_l + LBv, beta_l + LBv, Wout, bout, out);
}

// Round 10
// 446.838 us; speedup vs baseline: 1.1556x; 1.1556x over previous
//
#include <hip/hip_runtime.h>

#define NN 50000
#define EE 640000
#define DINv 64
#define GBv 128
#define GDv 4
#define LBv 256
#define LDv 2
#define GGv 1024

#define NB 196       // coarse buckets (256 nodes each)
#define BCAP 4096    // bucket capacity
#define BTILE 4096   // edges per k_bucket block
#define NBT ((EE + BTILE - 1) / BTILE)  // 157

#define NTILES ((NN + 63) / 64)  // 782 row-tiles
#define UPN (NN * 16)            // uprep float4 groups
#define CONVN (DINv * GBv + GDv * GBv * GBv)

typedef _Float16 f16x8 __attribute__((ext_vector_type(8)));
typedef float f32x4 __attribute__((ext_vector_type(4)));

__device__ __forceinline__ float h2f(ushort u) {
  union { ushort u; _Float16 h; } x;
  x.u = u;
  return (float)x.h;
}
__device__ __forceinline__ ushort f2h(float f) {
  union { ushort u; _Float16 h; } x;
  x.h = (_Float16)f;
  return x.u;
}

// ---------------- stage 1: coarse bucket sort (dst>>8) ----------------

__global__ __launch_bounds__(256) void k_bucket(const int* __restrict__ ei,
                                                int* __restrict__ bcnt,
                                                uint* __restrict__ bkt) {
  __shared__ int lcnt[NB];
  __shared__ int lbase[NB];
  __shared__ int gbase[NB];
  __shared__ int ls[256];
  __shared__ uint stage[BTILE];
  __shared__ ushort sb[BTILE];
  int tid = threadIdx.x;
  int t0 = blockIdx.x * BTILE;
  int cnt = min(BTILE, EE - t0);
  for (int i = tid; i < NB; i += 256) lcnt[i] = 0;
  __syncthreads();

  uint en[16];
  int bb[16], rk[16];
  int nper = (cnt + 255) >> 8;
  for (int k = 0; k < nper; k++) {
    int e = k * 256 + tid;
    if (e < cnt) {
      int src = ei[t0 + e];
      int dst = ei[EE + t0 + e];
      int b = dst >> 8;
      en[k] = ((uint)src << 8) | (uint)(dst & 255);
      bb[k] = b;
      rk[k] = atomicAdd(&lcnt[b], 1);
    } else {
      bb[k] = -1;
    }
  }
  __syncthreads();

  int v = (tid < NB) ? lcnt[tid] : 0;
  ls[tid] = v;
  __syncthreads();
  for (int off = 1; off < 256; off <<= 1) {
    int t = (tid >= off) ? ls[tid - off] : 0;
    __syncthreads();
    ls[tid] += t;
    __syncthreads();
  }
  if (tid < NB) {
    lbase[tid] = ls[tid] - v;
    gbase[tid] = atomicAdd(&bcnt[tid], v);
  }
  __syncthreads();

  for (int k = 0; k < nper; k++) {
    if (bb[k] >= 0) {
      int slot = lbase[bb[k]] + rk[k];
      stage[slot] = en[k];
      sb[slot] = (ushort)bb[k];
    }
  }
  __syncthreads();

  for (int i = tid; i < cnt; i += 256) {
    int b = sb[i];
    bkt[(size_t)b * BCAP + gbase[b] + (i - lbase[b])] = stage[i];
  }
}

__global__ __launch_bounds__(256) void k_bscan(const int* __restrict__ bcnt,
                                               int* __restrict__ bbase,
                                               int* __restrict__ offs) {
  __shared__ int ls[256];
  int tid = threadIdx.x;
  int v = (tid < NB) ? bcnt[tid] : 0;
  ls[tid] = v;
  __syncthreads();
  for (int off = 1; off < 256; off <<= 1) {
    int t = (tid >= off) ? ls[tid - off] : 0;
    __syncthreads();
    ls[tid] += t;
    __syncthreads();
  }
  if (tid < NB) bbase[tid] = ls[tid] - v;
  if (tid == 0) offs[NN] = EE;
}

// ---------------- stage 2: per-bucket fine CSR + deg/dinv/offs + degree hist ----------

__global__ __launch_bounds__(256) void k_csr(const uint* __restrict__ bkt,
                                             const int* __restrict__ bcnt,
                                             const int* __restrict__ bbase,
                                             int* __restrict__ offs,
                                             float* __restrict__ dinv,
                                             int* __restrict__ col,
                                             int* __restrict__ deg,
                                             int* __restrict__ ghist) {
  __shared__ int lhist[256];
  __shared__ int lofs[256];
  __shared__ int lcur[256];
  __shared__ int lh2[64];
  int b = blockIdx.x;
  int cnt = bcnt[b], base = bbase[b];
  const uint* B = bkt + (size_t)b * BCAP;
  int tid = threadIdx.x;
  lhist[tid] = 0;
  if (tid < 64) lh2[tid] = 0;
  __syncthreads();
  for (int i = tid; i < cnt; i += 256) atomicAdd(&lhist[B[i] & 255], 1);
  __syncthreads();
  int v = lhist[tid];
  lofs[tid] = v;
  __syncthreads();
  for (int off = 1; off < 256; off <<= 1) {
    int t = (tid >= off) ? lofs[tid - off] : 0;
    __syncthreads();
    lofs[tid] += t;
    __syncthreads();
  }
  int excl = lofs[tid] - v;
  int n = b * 256 + tid;
  if (n < NN) {
    offs[n] = base + excl;
    dinv[n] = rsqrtf((float)(v + 1));
    int d = min(v, 63);
    deg[n] = d;
    atomicAdd(&lh2[d], 1);
  }
  lcur[tid] = excl;
  __syncthreads();
  if (tid < 64 && lh2[tid]) atomicAdd(&ghist[tid], lh2[tid]);
  for (int i = tid; i < cnt; i += 256) {
    uint e = B[i];
    int p = atomicAdd(&lcur[e & 255], 1);
    col[base + p] = (int)(e >> 8);
  }
}

// degree-bin cursor: exclusive scan of 64 bins
__global__ void k_dscan(const int* __restrict__ ghist, int* __restrict__ dcur) {
  if (threadIdx.x == 0 && blockIdx.x == 0) {
    int run = 0;
    for (int i = 0; i < 64; i++) {
      dcur[i] = run;
      run += ghist[i];
    }
  }
}

// build degree-sorted permutation (block-local ranks + per-bin base reservation)
__global__ __launch_bounds__(256) void k_dperm(const int* __restrict__ deg,
                                               int* __restrict__ dcur,
                                               int* __restrict__ perm) {
  __shared__ int lhist[64];
  __shared__ int lbase[64];
  int tid = threadIdx.x;
  if (tid < 64) lhist[tid] = 0;
  __syncthreads();
  int n = blockIdx.x * 256 + tid;
  int d = 0, rk = 0;
  if (n < NN) {
    d = deg[n];
    rk = atomicAdd(&lhist[d], 1);
  }
  __syncthreads();
  if (tid < 64 && lhist[tid]) lbase[tid] = atomicAdd(&dcur[tid], lhist[tid]);
  __syncthreads();
  if (n < NN) perm[lbase[d] + rk] = n;
}

// ---------------- merged prep: u = f16(x*dinv)  +  Wt[c][k] = f16(W[k][c]) ----------

__global__ __launch_bounds__(256) void k_prep(const float* __restrict__ x,
                                              const float* __restrict__ dinv,
                                              const float* __restrict__ W0,
                                              const float* __restrict__ Wg,
                                              ushort* __restrict__ u,
                                              ushort* __restrict__ Wt0,
                                              ushort* __restrict__ Wtg) {
  int idx = blockIdx.x * 256 + threadIdx.x;
  if (idx < UPN) {
    int n = idx >> 4;
    float4 v = ((const float4*)x)[idx];
    float d = dinv[n];
    union { ushort us[4]; uint2 q; } o;
    o.us[0] = f2h(v.x * d);
    o.us[1] = f2h(v.y * d);
    o.us[2] = f2h(v.z * d);
    o.us[3] = f2h(v.w * d);
    ((uint2*)u)[idx] = o.q;
  } else {
    int j = idx - UPN;
    if (j < DINv * GBv) {
      int c = j >> 6, k = j & 63;
      Wt0[j] = f2h(W0[k * GBv + c]);
    } else if (j < CONVN) {
      int e = j - DINv * GBv;
      int i = e >> 14, rem = e & 16383;
      int c = rem >> 7, k = rem & 127;
      Wtg[e] = f2h(Wg[i * GBv * GBv + k * GBv + c]);
    }
  }
}

// ---------------- CSR aggregate (degree-sorted, whole-row gather) ----------------
// Node order via perm (degree-sorted) so each wave's 4 quads have ~equal degree.
// V[n] = f16( dinv[n] * ( row(n) + sum_src row(src) ) )
// row(s) = MODE0: Gin[s]; MODE1: relu(Gin[s])*dinv[s]; MODE2: relu(Gin[s]*S+T)*dinv[s]

template <int K, int MODE>
__global__ __launch_bounds__(256) void k_agg(const ushort* __restrict__ Gin,
                                             const int* __restrict__ col,
                                             const int* __restrict__ offs,
                                             const float* __restrict__ dinv,
                                             const int* __restrict__ perm,
                                             const float* __restrict__ st,
                                             const float* __restrict__ gamma,
                                             const float* __restrict__ beta,
                                             ushort* __restrict__ V) {
  constexpr int VEC = K / 16;
  __shared__ float sS[128], sT[128];
  int tid = threadIdx.x;
  if constexpr (MODE == 2) {
    if (tid < 128) {
      float mu = st[tid] * (1.f / NN);
      float var = st[128 + tid] * (1.f / NN) - mu * mu;
      float s = rsqrtf(var + 1e-5f) * gamma[tid];
      sS[tid] = s;
      sT[tid] = beta[tid] - mu * s;
    }
    __syncthreads();
  }
  int lane = tid & 63;
  int q = lane >> 4, m = lane & 15;
  int idx = blockIdx.x * 16 + (tid >> 6) * 4 + q;  // 3125*16 = 50000 exact
  int n = perm[idx];

  float sc[VEC], tc[VEC];
  if constexpr (MODE == 2) {
#pragma unroll
    for (int v = 0; v < VEC; v++) {
      sc[v] = sS[m * VEC + v];
      tc[v] = sT[m * VEC + v];
    }
  }

  union U { uint4 v4; uint2 v2; ushort us[8]; };
  auto loadrow = [&](int s) {
    U u;
    const ushort* p = Gin + (long)s * K + m * VEC;
    if constexpr (VEC == 8) u.v4 = *(const uint4*)p;
    else u.v2 = *(const uint2*)p;
    return u;
  };
  float acc[VEC];
#pragma unroll
  for (int v = 0; v < VEC; v++) acc[v] = 0.f;
  auto addrow = [&](U u, float dv) {
#pragma unroll
    for (int v = 0; v < VEC; v++) {
      float g = h2f(u.us[v]);
      if constexpr (MODE == 0) acc[v] += g;
      else if constexpr (MODE == 1) acc[v] += fmaxf(g, 0.f) * dv;
      else acc[v] += fmaxf(g * sc[v] + tc[v], 0.f) * dv;
    }
  };

  float dn = dinv[n];
  addrow(loadrow(n), dn);

  int s0 = offs[n], s1 = offs[n + 1];
  int j = s0;
  for (; j + 7 < s1; j += 8) {
    int si[8];
#pragma unroll
    for (int t = 0; t < 8; t++) si[t] = col[j + t];
    U uu[8];
#pragma unroll
    for (int t = 0; t < 8; t++) uu[t] = loadrow(si[t]);
    float dd[8];
#pragma unroll
    for (int t = 0; t < 8; t++) dd[t] = (MODE != 0) ? dinv[si[t]] : 0.f;
#pragma unroll
    for (int t = 0; t < 8; t++) addrow(uu[t], dd[t]);
  }
  for (; j + 3 < s1; j += 4) {
    int si[4];
#pragma unroll
    for (int t = 0; t < 4; t++) si[t] = col[j + t];
    U uu[4];
#pragma unroll
    for (int t = 0; t < 4; t++) uu[t] = loadrow(si[t]);
    float dd[4];
#pragma unroll
    for (int t = 0; t < 4; t++) dd[t] = (MODE != 0) ? dinv[si[t]] : 0.f;
#pragma unroll
    for (int t = 0; t < 4; t++) addrow(uu[t], dd[t]);
  }
  for (; j < s1; j++) {
    int s = col[j];
    U u = loadrow(s);
    float dv = (MODE != 0) ? dinv[s] : 0.f;
    addrow(u, dv);
  }

  U o;
#pragma unroll
  for (int v = 0; v < VEC; v++) o.us[v] = f2h(acc[v] * dn);
  ushort* op = V + (long)n * K + m * VEC;
  if constexpr (VEC == 8) *(uint4*)op = o.v4;
  else *(uint2*)op = o.v2;
}

// ---------------- MFMA matmul: g[r][c] = f16( (V @ W)[r][c] + b[c] ), fused stats ----

template <int K, bool STATS>
__global__ __launch_bounds__(256) void k_mm(const ushort* __restrict__ X,
                                            const ushort* __restrict__ Wt,
                                            const float* __restrict__ bias,
                                            float* __restrict__ stG,
                                            ushort* __restrict__ Gout) {
  constexpr int KP = K + 8;
  constexpr int CP = 136;
  constexpr bool REUSE = (K == 128);
  __shared__ __attribute__((aligned(16))) _Float16 sW[128 * KP];
  __shared__ __attribute__((aligned(16))) _Float16 sA[64 * KP];
  __shared__ __attribute__((aligned(16))) _Float16 sCbuf[REUSE ? 8 : 64 * CP];
  __shared__ float sB[128];
  __shared__ float ssum[128], ssq[128];
  _Float16* sC = REUSE ? sA : sCbuf;
  int tid = threadIdx.x;

  {
    constexpr int CH = K / 8;
    for (int i = tid; i < 128 * CH; i += 256) {
      int c = i / CH, ch = i - c * CH;
      *(uint4*)&sW[c * KP + ch * 8] = ((const uint4*)Wt)[i];
    }
  }
  if (tid < 128) {
    sB[tid] = bias[tid];
    if constexpr (STATS) {
      ssum[tid] = 0.f;
      ssq[tid] = 0.f;
    }
  }

  int w = tid >> 6, lane = tid & 63;
  int m = lane & 15, quad = lane >> 4;
  int crow = 16 * w + quad * 4;

  float ps[8], pq[8];
  if constexpr (STATS) {
#pragma unroll
    for (int ct = 0; ct < 8; ct++) { ps[ct] = 0.f; pq[ct] = 0.f; }
  }

  for (int tile = blockIdx.x; tile < NTILES; tile += gridDim.x) {
    int row0 = tile * 64;
    __syncthreads();

    {
      int r = tid >> 2, col0 = (tid & 3) * (K / 4);
      int gr = row0 + r;
      const uint4* p = (const uint4*)(X + (long)gr * K + col0);
#pragma unroll
      for (int ch = 0; ch < K / 32; ch++) {
        uint4 v = (gr < NN) ? p[ch] : make_uint4(0, 0, 0, 0);
        *(uint4*)&sA[r * KP + col0 + ch * 8] = v;
      }
    }
    __syncthreads();

    f32x4 acc[8];
#pragma unroll
    for (int ct = 0; ct < 8; ct++) acc[ct] = (f32x4){0.f, 0.f, 0.f, 0.f};
    const _Float16* pa = &sA[(16 * w + m) * KP + quad * 8];
#pragma unroll
    for (int ks = 0; ks < K; ks += 32) {
      f16x8 a = *(const f16x8*)(pa + ks);
#pragma unroll
      for (int ct = 0; ct < 8; ct++) {
        f16x8 b = *(const f16x8*)&sW[(ct * 16 + m) * KP + ks + quad * 8];
        acc[ct] = __builtin_amdgcn_mfma_f32_16x16x32_f16(a, b, acc[ct], 0, 0, 0);
      }
    }

    if constexpr (STATS) {
#pragma unroll
      for (int ct = 0; ct < 8; ct++) {
        int c = ct * 16 + m;
        float b = sB[c];
#pragma unroll
        for (int r = 0; r < 4; r++) {
          if (row0 + crow + r < NN) {
            float g = acc[ct][r] + b;
            ps[ct] += g;
            pq[ct] += g * g;
          }
        }
      }
    }
    if constexpr (REUSE) __syncthreads();

#pragma unroll
    for (int ct = 0; ct < 8; ct++) {
      int c = ct * 16 + m;
      float b = sB[c];
#pragma unroll
      for (int r = 0; r < 4; r++) sC[(crow + r) * CP + c] = (_Float16)(acc[ct][r] + b);
    }
    __syncthreads();

    {
      int r = tid >> 2, col0 = (tid & 3) * 32;
      int gr = row0 + r;
      if (gr < NN) {
        const uint4* src = (const uint4*)&sC[r * CP + col0];
        uint4* dst = (uint4*)(Gout + (long)gr * 128 + col0);
#pragma unroll
        for (int ch = 0; ch < 4; ch++) dst[ch] = src[ch];
      }
    }
  }

  if constexpr (STATS) {
#pragma unroll
    for (int ct = 0; ct < 8; ct++) {
      float s = ps[ct], q = pq[ct];
      s += __shfl_xor(s, 16);
      q += __shfl_xor(q, 16);
      s += __shfl_xor(s, 32);
      q += __shfl_xor(q, 32);
      if (quad == 0) {
        atomicAdd(&ssum[ct * 16 + m], s);
        atomicAdd(&ssq[ct * 16 + m], q);
      }
    }
    __syncthreads();
    if (tid < 128) {
      int c = (tid + blockIdx.x * 8) & 127;
      atomicAdd(&stG[c], ssum[c]);
      atomicAdd(&stG[128 + c], ssq[c]);
    }
  }
}

// ---------------- pool: per-graph segmented reduction (batch sorted) ----------------

__global__ __launch_bounds__(128) void k_pool2(const ushort* __restrict__ G,
                                               const float* __restrict__ st,
                                               const float* __restrict__ gamma,
                                               const float* __restrict__ beta,
                                               const int* __restrict__ batch,
                                               float* __restrict__ hp) {
  __shared__ int sse[2];
  int g = blockIdx.x;
  int c = threadIdx.x;
  if (c < 2) {
    int key = g + c;
    int lo = 0, hi = NN;
    while (lo < hi) {
      int mid = (lo + hi) >> 1;
      if (batch[mid] < key) lo = mid + 1;
      else hi = mid;
    }
    sse[c] = lo;
  }
  __syncthreads();
  int s = sse[0], e = sse[1];
  float m = st[c] * (1.f / NN);
  float v = st[128 + c] * (1.f / NN) - m * m;
  float sc = rsqrtf(v + 1e-5f) * gamma[c];
  float tc = beta[c] - m * sc;
  float acc = 0.f;
  for (int n = s; n < e; n++) acc += fmaxf(h2f(G[(long)n * 128 + c]) * sc + tc, 0.f);
  hp[(long)g * 128 + c] = acc;
}

// ---------------- head column stats (fp32) ----------------

__global__ void k_colstats(const float* __restrict__ X, int rows, float* __restrict__ st) {
  int c = threadIdx.x;
  int C = blockDim.x;
  float s = 0.f, q = 0.f;
  for (int r = blockIdx.x; r < rows; r += gridDim.x) {
    float v = X[(long)r * C + c];
    s += v;
    q += v * v;
  }
  atomicAdd(&st[c], s);
  atomicAdd(&st[C + c], q);
}

// ---------------- MLP head ----------------

template <int KIN, int MODE>
__global__ __launch_bounds__(256) void k_fc(const float* __restrict__ X,
                                            const float* __restrict__ W,
                                            const float* __restrict__ b,
                                            const float* __restrict__ st,
                                            const float* __restrict__ gamma,
                                            const float* __restrict__ beta,
                                            float* __restrict__ Y) {
  __shared__ float sx[KIN];
  int g = blockIdx.x;
  int c = threadIdx.x;
  for (int k = c; k < KIN; k += 256) {
    float v = X[(long)g * KIN + k];
    if constexpr (MODE == 2) {
      float m = st[k] * (1.f / GGv);
      float var = st[KIN + k] * (1.f / GGv) - m * m;
      v = fmaxf((v - m) * rsqrtf(var + 1e-5f) * gamma[k] + beta[k], 0.f);
    }
    sx[k] = v;
  }
  __syncthreads();
  float acc = b[c];
#pragma unroll 8
  for (int k = 0; k < KIN; k++) acc += sx[k] * W[(long)k * 256 + c];
  Y[(long)g * 256 + c] = (MODE == 0) ? fmaxf(acc, 0.f) : acc;
}

__global__ __launch_bounds__(256) void k_out(const float* __restrict__ X,
                                             const float* __restrict__ st,
                                             const float* __restrict__ gamma,
                                             const float* __restrict__ beta,
                                             const float* __restrict__ Wout,
                                             const float* __restrict__ bout,
                                             float* __restrict__ out) {
  int g = blockIdx.x * 4 + (threadIdx.x >> 6);
  int l = threadIdx.x & 63;
  float a0 = 0.f, a1 = 0.f;
  for (int k = l; k < LBv; k += 64) {
    float z = X[(long)g * LBv + k];
    float m = st[k] * (1.f / GGv);
    float var = st[LBv + k] * (1.f / GGv) - m * m;
    float x = fmaxf((z - m) * rsqrtf(var + 1e-5f) * gamma[k] + beta[k], 0.f);
    a0 += x * Wout[2 * k];
    a1 += x * Wout[2 * k + 1];
  }
  for (int off = 32; off > 0; off >>= 1) {
    a0 += __shfl_down(a0, off);
    a1 += __shfl_down(a1, off);
  }
  if (l == 0) {
    out[2 * g] = a0 + bout[0];
    out[2 * g + 1] = a1 + bout[1];
  }
}

// ---------------- launch ----------------

extern "C" void kernel_launch(void* const* d_in, const int* in_sizes, int n_in,
                              void* d_out, int out_size, void* d_ws, size_t ws_size,
                              hipStream_t stream) {
  const float* x = (const float*)d_in[0];
  const int* ei = (const int*)d_in[1];
  const int* batch = (const int*)d_in[2];
  const float* W0 = (const float*)d_in[4];
  const float* b0 = (const float*)d_in[5];
  const float* Wg = (const float*)d_in[6];
  const float* bg = (const float*)d_in[7];
  const float* gamma_g = (const float*)d_in[8];
  const float* beta_g = (const float*)d_in[9];
  const float* Wl0 = (const float*)d_in[10];
  const float* bl0 = (const float*)d_in[11];
  const float* Wl = (const float*)d_in[12];
  const float* bl = (const float*)d_in[13];
  const float* gamma_l = (const float*)d_in[14];
  const float* beta_l = (const float*)d_in[15];
  const float* Wout = (const float*)d_in[16];
  const float* bout = (const float*)d_in[17];
  float* out = (float*)d_out;

  char* w = (char*)d_ws;
  auto alloc = [&](size_t bytes) {
    void* p = (void*)w;
    w += (bytes + 255) & ~(size_t)255;
    return p;
  };
  // zero-initialized span: bcnt | stAll | ghist
  int* bcnt = (int*)alloc((size_t)NB * 4);
  float* stAll = (float*)alloc((size_t)(4 * 256 + 2 * 512) * 4);
  int* ghist = (int*)alloc((size_t)64 * 4);
  size_t zspan = (char*)w - (char*)bcnt;
  // rest
  uint* bkt = (uint*)alloc((size_t)NB * BCAP * 4);
  int* bbase = (int*)alloc((size_t)NB * 4);
  int* offs = (int*)alloc((size_t)(NN + 1) * 4);
  int* col = (int*)alloc((size_t)EE * 4);
  float* dinv = (float*)alloc((size_t)NN * 4);
  int* deg = (int*)alloc((size_t)NN * 4);
  int* perm = (int*)alloc((size_t)NN * 4);
  int* dcur = (int*)alloc((size_t)64 * 4);
  ushort* u = (ushort*)alloc((size_t)NN * DINv * 2);
  ushort* V = (ushort*)alloc((size_t)NN * GBv * 2);
  ushort* g = (ushort*)alloc((size_t)NN * GBv * 2);
  ushort* Wt0 = (ushort*)alloc((size_t)DINv * GBv * 2);
  ushort* Wtg = (ushort*)alloc((size_t)GDv * GBv * GBv * 2);
  float* hp = (float*)alloc((size_t)GGv * GBv * 4);
  float* m1 = (float*)alloc((size_t)GGv * LBv * 4);
  float* m2 = (float*)alloc((size_t)GGv * LBv * 4);

  float* stg = stAll;
  float* sth0 = stAll + 4 * 256;
  float* sth1 = sth0 + 512;

  hipMemsetAsync(bcnt, 0, zspan, stream);

  k_bucket<<<NBT, 256, 0, stream>>>(ei, bcnt, bkt);
  k_bscan<<<1, 256, 0, stream>>>(bcnt, bbase, offs);
  k_csr<<<NB, 256, 0, stream>>>(bkt, bcnt, bbase, offs, dinv, col, deg, ghist);
  k_dscan<<<1, 64, 0, stream>>>(ghist, dcur);
  k_dperm<<<NB, 256, 0, stream>>>(deg, dcur, perm);
  k_prep<<<(UPN + CONVN + 255) / 256, 256, 0, stream>>>(x, dinv, W0, Wg, u, Wt0, Wtg);

  const int AGG = NN / 16;  // 3125
  const int MMG = 512;      // persistent-W grid-stride blocks

  // layer 0
  k_agg<64, 0><<<AGG, 256, 0, stream>>>(u, col, offs, dinv, perm, nullptr, nullptr,
                                        nullptr, V);
  k_mm<64, false><<<MMG, 256, 0, stream>>>(V, Wt0, b0, nullptr, g);

  // layer 1 (relu fold)
  k_agg<128, 1><<<AGG, 256, 0, stream>>>(g, col, offs, dinv, perm, nullptr, nullptr,
                                         nullptr, V);
  k_mm<128, true><<<MMG, 256, 0, stream>>>(V, Wtg, bg, stg, g);

  // layers 2..4 (BN+relu fold)
  for (int i = 1; i < GDv; i++) {
    k_agg<128, 2><<<AGG, 256, 0, stream>>>(g, col, offs, dinv, perm,
                                           stg + (size_t)(i - 1) * 256,
                                           gamma_g + (size_t)(i - 1) * GBv,
                                           beta_g + (size_t)(i - 1) * GBv, V);
    k_mm<128, true><<<MMG, 256, 0, stream>>>(V, Wtg + (size_t)i * GBv * GBv,
                                             bg + (size_t)i * GBv, stg + (size_t)i * 256, g);
  }

  // pool with final BN+relu fused
  k_pool2<<<GGv, 128, 0, stream>>>(g, stg + 3 * 256, gamma_g + 3 * GBv, beta_g + 3 * GBv,
                                   batch, hp);

  // head
  k_fc<GBv, 0><<<GGv, 256, 0, stream>>>(hp, Wl0, bl0, nullptr, nullptr, nullptr, m1);
  k_fc<LBv, 1><<<GGv, 256, 0, stream>>>(m1, Wl, bl, nullptr, nullptr, nullptr, m2);
  k_colstats<<<256, LBv, 0, stream>>>(m2, GGv, sth0);
  k_fc<LBv, 2><<<GGv, 256, 0, stream>>>(m2, Wl + (size_t)LBv * LBv, bl + LBv, sth0,
                                        gamma_l, beta_l, m1);
  k_colstats<<<256, LBv, 0, stream>>>(m1, GGv, sth1);
  k_out<<<GGv / 4, 256, 0, stream>>>(m1, sth1, gamma_l + LBv, beta_l + LBv, Wout, bout, out);
}